// Round 11
// baseline (324.296 us; speedup 1.0000x reference)
//
#include <hip/hip_runtime.h>
#include <hip/hip_bf16.h>

// Sizes fixed by the reference
#define HV   128
#define HT   17
#define DIMD 290        // 2*(HV+HT)
#define KP   320        // K padded to 10*32 for mfma 16x16x32
#define OO   640        // 5*HV
#define RT   64         // rows per tile
#define KN   8          // number of types
#define GG   256        // persistent grid (1 block/CU; tiles strided by GG)

typedef unsigned short u16;
typedef __attribute__((ext_vector_type(8))) short short8v;
typedef __attribute__((ext_vector_type(4))) float f32x4;

__device__ __forceinline__ u16 f2bf(float x) {
    unsigned u = __float_as_uint(x);
    u = (u + 0x7FFFu + ((u >> 16) & 1u)) >> 16;   // RNE
    return (u16)u;
}
__device__ __forceinline__ float sigf(float x) {
    return __builtin_amdgcn_rcpf(1.0f + __expf(-x));
}
__device__ __forceinline__ float tanhfast(float x) {
    return 1.0f - 2.0f * __builtin_amdgcn_rcpf(1.0f + __expf(2.0f * x));
}

// ws header layout (ints): [0..7] counts, [8..15] scatter cursors,
// [16..24] blkStart prefix (blkStart[8] = total row-tiles)

__global__ void hist_k(const int* __restrict__ pt, int* __restrict__ hdr, int N) {
    __shared__ int c[KN];
    if (threadIdx.x < KN) c[threadIdx.x] = 0;
    __syncthreads();
    int n = blockIdx.x * 256 + threadIdx.x;
    if (n < N) atomicAdd(&c[pt[n]], 1);
    __syncthreads();
    if (threadIdx.x < KN && c[threadIdx.x]) atomicAdd(&hdr[threadIdx.x], c[threadIdx.x]);
}

__global__ void prefix_k(int* __restrict__ hdr) {
    if (threadIdx.x == 0 && blockIdx.x == 0) {
        int acc = 0;
        hdr[16] = 0;
        for (int k = 0; k < KN; ++k) {
            acc += (hdr[k] + RT - 1) / RT;
            hdr[17 + k] = acc;
        }
    }
}

__global__ void scatter_k(const int* __restrict__ pt, int* __restrict__ hdr,
                          int* __restrict__ idxbuf, int N) {
    __shared__ int c[KN], base[KN];
    if (threadIdx.x < KN) c[threadIdx.x] = 0;
    __syncthreads();
    int n = blockIdx.x * 256 + threadIdx.x;
    int k = 0, my = 0;
    if (n < N) { k = pt[n]; my = atomicAdd(&c[k], 1); }
    __syncthreads();
    if (threadIdx.x < KN)
        base[threadIdx.x] = c[threadIdx.x] ? atomicAdd(&hdr[8 + threadIdx.x], c[threadIdx.x]) : 0;
    __syncthreads();
    if (n < N) idxbuf[hdr[16 + k] * RT + base[k] + my] = n;
}

// W (K,O,290) fp32 -> Wt (K, 10, 640, 32) bf16, K-major-tiled + column perm.
// x' layout = [h_l 0..128 | h_r 128..256 | t_l 256..273 | t_r 273..290 | 0 pad]
__global__ void wconv_k(const float* __restrict__ W, u16* __restrict__ Wt) {
    int k = blockIdx.y;
    int idx = blockIdx.x * 256 + threadIdx.x;
    if (idx >= OO * KP) return;
    int o = idx / KP, d = idx % KP;
    int src;
    if (d < 256)      src = (d < 128) ? d : d + 17;
    else if (d < 273) src = d - 128;
    else if (d < 290) src = d;
    else              src = -1;
    float v = (src >= 0) ? W[((size_t)k * OO + o) * DIMD + src] : 0.0f;
    int kk = d >> 5, e = d & 31;
    Wt[(((size_t)k * 10 + kk) * OO + o) * 32 + e] = f2bf(v);
}

// Persistent fused kernel: 1 block/CU, tiles strided by GG, LDS double-buffered.
// Per tile: {c-prefetch(t) -> LDS-write(t+1) from held regs -> issue gather(t+2)
// -> MFMA(t) -> epilogue(t) -> lgkm-only barrier}. Stores and gather loads stay
// in flight across the barrier (no vmcnt drain).
__global__ __launch_bounds__(512, 2)
void fusedp_k(const float* __restrict__ h_pool, const float* __restrict__ c_pool,
              const float* __restrict__ t_pool, const int* __restrict__ child_idx,
              const float* __restrict__ bias, const u16* __restrict__ Wt,
              const int* __restrict__ hdr, const int* __restrict__ idxbuf,
              float* __restrict__ out) {
    __shared__ u16 sX[2][RT * KP];        // 2 x 40960 B
    __shared__ int4 sMeta[2][RT];

    const int ntiles = hdr[24];
    const int bx = blockIdx.x;
    if (bx >= ntiles) return;

    const int tid = threadIdx.x;
    const int r = tid >> 3, q = tid & 7;     // 8 threads per row

    float4 A0[4], B0[4];
    float Tl0, Tl1, Tl2 = 0.f, Tr0, Tr1, Tr2 = 0.f;
    int sn, sl, sr2;

    auto loadmeta = [&](int tile) {
        sn = idxbuf[tile * RT + r];
        sl = 0; sr2 = 0;
        if (sn >= 0) { sl = child_idx[2 * sn]; sr2 = child_idx[2 * sn + 1]; }
    };
    auto issue_stage = [&]() {
        if (sn < 0) return;
        const float4* hl = (const float4*)(h_pool + (size_t)sl * HV);
        const float4* hr = (const float4*)(h_pool + (size_t)sr2 * HV);
        #pragma unroll
        for (int m = 0; m < 4; ++m) A0[m] = hl[q + 8 * m];
        #pragma unroll
        for (int m = 0; m < 4; ++m) B0[m] = hr[q + 8 * m];
        const float* tl = t_pool + (size_t)sl * HT;
        const float* tr = t_pool + (size_t)sr2 * HT;
        Tl0 = tl[q]; Tl1 = tl[q + 8];
        Tr0 = tr[q]; Tr1 = tr[q + 8];
        if (q == 0) { Tl2 = tl[16]; Tr2 = tr[16]; }
    };
    auto write_stage = [&](int pb) {
        char* xr = (char*)sX[pb] + r * 640;
        const int swz = (r & 7) << 4;
        if (sn >= 0) {
            #pragma unroll
            for (int m = 0; m < 4; ++m) {
                float4 v = A0[m];
                *(ushort4*)(xr + (((q + 8 * m) * 8) ^ swz)) =
                    make_ushort4(f2bf(v.x), f2bf(v.y), f2bf(v.z), f2bf(v.w));
            }
            #pragma unroll
            for (int m = 0; m < 4; ++m) {
                float4 v = B0[m];
                *(ushort4*)(xr + ((256 + (q + 8 * m) * 8) ^ swz)) =
                    make_ushort4(f2bf(v.x), f2bf(v.y), f2bf(v.z), f2bf(v.w));
            }
            *(u16*)(xr + ((512 + 2 * q) ^ swz))       = f2bf(Tl0);
            *(u16*)(xr + ((512 + 2 * (q + 8)) ^ swz)) = f2bf(Tl1);
            *(u16*)(xr + ((546 + 2 * q) ^ swz))       = f2bf(Tr0);
            *(u16*)(xr + ((546 + 2 * (q + 8)) ^ swz)) = f2bf(Tr1);
            if (q == 0) {
                *(u16*)(xr + (544 ^ swz)) = f2bf(Tl2);
                *(u16*)(xr + (578 ^ swz)) = f2bf(Tr2);
            }
            for (int b = 580 + 2 * q; b < 640; b += 16)
                *(u16*)(xr + (b ^ swz)) = 0;
        } else {
            ushort4 z = make_ushort4(0, 0, 0, 0);
            for (int b = q * 8; b < 640; b += 64)
                *(ushort4*)(xr + (b ^ swz)) = z;
        }
    };

    // ---- prolog: stage tile bx into buf0; hold gather(bx+GG) in regs ----
    loadmeta(bx);
    if (q == 0) sMeta[0][r] = make_int4(sn, sl, sr2, 0);
    issue_stage();
    write_stage(0);
    if (bx + GG < ntiles) { loadmeta(bx + GG); issue_stage(); }
    __syncthreads();

    const int wc = tid >> 6, lane = tid & 63;
    const int lo = lane & 15, hi = lane >> 4;
    const int hcol = wc * 16 + lo;
    const int rowbase = lo * 640;
    const int swzl = (lo & 7) << 4;
    int wo[5];
    #pragma unroll
    for (int g = 0; g < 5; ++g)
        wo[g] = (g * 128 + hcol) * 32 + hi * 8;

    int p = 0;
    for (int t = bx; t < ntiles; t += GG) {
        const char* sXb = (const char*)sX[p];

        // ---- 1. type + c/bias prefetch for t (hides under MFMA) ----
        int k = 0;
        #pragma unroll
        for (int j = 0; j < 7; ++j) k += (t >= hdr[17 + j]);

        float cpl[16], cpr[16];
        #pragma unroll
        for (int m = 0; m < 4; ++m)
            #pragma unroll
            for (int jj = 0; jj < 4; ++jj) {
                int4 mt = sMeta[p][m * 16 + hi * 4 + jj];
                cpl[m * 4 + jj] = c_pool[(size_t)mt.y * HV + hcol];
                cpr[m * 4 + jj] = c_pool[(size_t)mt.z * HV + hcol];
            }
        float bb[5];
        #pragma unroll
        for (int g = 0; g < 5; ++g) bb[g] = bias[k * OO + g * 128 + hcol];

        // ---- 2. LDS-write tile t+GG (regs held from last iteration) ----
        const bool hasn1 = (t + GG < ntiles);
        if (hasn1) {
            if (q == 0) sMeta[p ^ 1][r] = make_int4(sn, sl, sr2, 0);
            write_stage(p ^ 1);
        }
        // ---- 3. issue gather for t+2*GG (arrives during MFMA) ----
        if (t + 2 * GG < ntiles) { loadmeta(t + 2 * GG); issue_stage(); }

        // ---- 4. MFMA loop (1-deep W lookahead) ----
        f32x4 acc[5][4];
        #pragma unroll
        for (int g = 0; g < 5; ++g)
            #pragma unroll
            for (int m = 0; m < 4; ++m)
                acc[g][m] = (f32x4){0.f, 0.f, 0.f, 0.f};

        const u16* __restrict__ wt = Wt + ((size_t)k * 10 * OO) * 32;
        short8v wfa[5], wfb[5];
        #pragma unroll
        for (int g = 0; g < 5; ++g) wfa[g] = *(const short8v*)(wt + wo[g]);

        #pragma unroll
        for (int kk = 0; kk < 10; ++kk) {
            short8v (&wcur)[5] = (kk & 1) ? wfb : wfa;
            short8v (&wnxt)[5] = (kk & 1) ? wfa : wfb;
            if (kk < 9) {
                const u16* wtn = wt + (size_t)(kk + 1) * (OO * 32);
                #pragma unroll
                for (int g = 0; g < 5; ++g)
                    wnxt[g] = *(const short8v*)(wtn + wo[g]);
            }
            int a_off = rowbase + ((kk * 64 + hi * 16) ^ swzl);
            short8v a0 = *(const short8v*)(sXb + a_off);
            short8v a1 = *(const short8v*)(sXb + a_off + 10240);
            short8v a2 = *(const short8v*)(sXb + a_off + 20480);
            short8v a3 = *(const short8v*)(sXb + a_off + 30720);
            #pragma unroll
            for (int g = 0; g < 5; ++g) {
                acc[g][0] = __builtin_amdgcn_mfma_f32_16x16x32_bf16(a0, wcur[g], acc[g][0], 0, 0, 0);
                acc[g][1] = __builtin_amdgcn_mfma_f32_16x16x32_bf16(a1, wcur[g], acc[g][1], 0, 0, 0);
                acc[g][2] = __builtin_amdgcn_mfma_f32_16x16x32_bf16(a2, wcur[g], acc[g][2], 0, 0, 0);
                acc[g][3] = __builtin_amdgcn_mfma_f32_16x16x32_bf16(a3, wcur[g], acc[g][3], 0, 0, 0);
            }
        }

        // ---- 5. fused LSTM epilogue ----
        #pragma unroll
        for (int m = 0; m < 4; ++m) {
            #pragma unroll
            for (int jj = 0; jj < 4; ++jj) {
                int4 mt = sMeta[p][m * 16 + hi * 4 + jj];
                if (mt.x < 0) continue;
                float cl = cpl[m * 4 + jj], cr = cpr[m * 4 + jj];
                float gi  = acc[0][m][jj] + bb[0];
                float gfl = acc[1][m][jj] + bb[1];
                float gfr = acc[2][m][jj] + bb[2];
                float gu  = acc[3][m][jj] + bb[3];
                float go  = acc[4][m][jj] + bb[4];
                float cc = sigf(gi) * tanhfast(gu) + sigf(gfl) * cl + sigf(gfr) * cr;
                float hh = sigf(go) * tanhfast(cc);
                float* orow = out + (size_t)mt.x * (2 * HV);
                orow[hcol]      = hh;
                orow[HV + hcol] = cc;
            }
        }

        // ---- 6. lgkm-only barrier: keep gather loads + stores in flight ----
        if (hasn1) {
            asm volatile("s_waitcnt lgkmcnt(0)" ::: "memory");
            __builtin_amdgcn_s_barrier();
            p ^= 1;
        }
    }
}

extern "C" void kernel_launch(void* const* d_in, const int* in_sizes, int n_in,
                              void* d_out, int out_size, void* d_ws, size_t ws_size,
                              hipStream_t stream) {
    const float* h_pool      = (const float*)d_in[0];
    const float* c_pool      = (const float*)d_in[1];
    const float* t_pool      = (const float*)d_in[2];
    const int*   child_idx   = (const int*)d_in[3];
    const int*   parent_type = (const int*)d_in[4];
    const float* W           = (const float*)d_in[5];
    const float* bias        = (const float*)d_in[6];
    float* out = (float*)d_out;

    const int N = in_sizes[3] / 2;
    const int maxblk = (N + RT - 1) / RT + KN;    // upper bound on row-tiles
    const int totrows = maxblk * RT;

    char* ws = (char*)d_ws;
    size_t off = 0;
    int* hdr = (int*)ws;                         off += 1024;
    int* idxbuf = (int*)(ws + off);              off += (((size_t)totrows * 4 + 255) / 256) * 256;
    u16* Wt = (u16*)(ws + off);                  off += (size_t)KN * OO * KP * 2;

    hipMemsetAsync(hdr, 0, 1024, stream);
    hipMemsetAsync(idxbuf, 0xFF, (size_t)totrows * 4, stream);

    int nb = (N + 255) / 256;
    hist_k<<<nb, 256, 0, stream>>>(parent_type, hdr, N);
    prefix_k<<<1, 64, 0, stream>>>(hdr);
    scatter_k<<<nb, 256, 0, stream>>>(parent_type, hdr, idxbuf, N);
    wconv_k<<<dim3((OO * KP + 255) / 256, KN), 256, 0, stream>>>(W, Wt);
    fusedp_k<<<GG, 512, 0, stream>>>(
        h_pool, c_pool, t_pool, child_idx, bias, Wt, hdr, idxbuf, out);
}